// Round 8
// baseline (366.111 us; speedup 1.0000x reference)
//
#include <hip/hip_runtime.h>
#include <hip/hip_bf16.h>
#include <stdint.h>

typedef __bf16 bf16_t;
typedef bf16_t bf16x8 __attribute__((ext_vector_type(8)));
typedef float f32x4 __attribute__((ext_vector_type(4)));

#define NN 10000

__device__ __forceinline__ float b2f(unsigned short u) {
  union { unsigned int i; float f; } c; c.i = ((unsigned int)u) << 16; return c.f;
}
__device__ __forceinline__ unsigned short f2b(float f) {
  union { float f; unsigned int i; } c; c.f = f;
  unsigned int x = c.i;
  x += 0x7FFFu + ((x >> 16) & 1u);
  return (unsigned short)(x >> 16);
}
__device__ __forceinline__ uint4 cvt8(float4 a, float4 b) {
  uint4 r;
  r.x = (unsigned int)f2b(a.x) | ((unsigned int)f2b(a.y) << 16);
  r.y = (unsigned int)f2b(a.z) | ((unsigned int)f2b(a.w) << 16);
  r.z = (unsigned int)f2b(b.x) | ((unsigned int)f2b(b.y) << 16);
  r.w = (unsigned int)f2b(b.z) | ((unsigned int)f2b(b.w) << 16);
  return r;
}
__device__ __forceinline__ void load_lds16(const void* g, void* l) {
  __builtin_amdgcn_global_load_lds(
      (const __attribute__((address_space(1))) unsigned int*)g,
      (__attribute__((address_space(3))) unsigned int*)l, 16, 0, 0);
}
__device__ __forceinline__ f32x4 mfma16(bf16x8 a, bf16x8 b, f32x4 c) {
  return __builtin_amdgcn_mfma_f32_16x16x32_bf16(a, b, c, 0, 0, 0);
}

// ---- GEMM tile (bf16 A via global_load_lds): C[128x128] @ (tm,tn) ----
template <bool OBF16>
__device__ void gemm_tile(const unsigned short* __restrict__ A, const unsigned short* __restrict__ Bt,
                          void* __restrict__ Cv, int M, int Ncols, int ldc, int tm, int tn)
{
  __shared__ __align__(16) unsigned short As[2][128 * 32];
  __shared__ __align__(16) unsigned short Bs[2][128 * 32];
  const int tid = threadIdx.x;
  const int lane = tid & 63;
  const int wm = (tid >> 6) >> 1;
  const int wn = (tid >> 6) & 1;
  const int quad = lane >> 4, l15 = lane & 15;

  const int r0 = tid >> 2, kc = tid & 3;
  int ga0 = tm * 128 + r0;       if (ga0 > M - 1) ga0 = M - 1;
  int ga1 = tm * 128 + 64 + r0;  if (ga1 > M - 1) ga1 = M - 1;
  const int gb0 = tn * 128 + r0;
  const int gb1 = tn * 128 + 64 + r0;
  const unsigned short* gA0 = A + (size_t)ga0 * 512 + kc * 8;
  const unsigned short* gA1 = A + (size_t)ga1 * 512 + kc * 8;
  const unsigned short* gB0 = Bt + (size_t)gb0 * 512 + kc * 8;
  const unsigned short* gB1 = Bt + (size_t)gb1 * 512 + kc * 8;
  const int loff0 = r0 * 32 + kc * 8;
  const int loff1 = (64 + r0) * 32 + kc * 8;

  f32x4 acc[4][4];
  #pragma unroll
  for (int i = 0; i < 4; i++)
    #pragma unroll
    for (int j = 0; j < 4; j++) {
      f32x4 z = {0.f, 0.f, 0.f, 0.f};
      acc[i][j] = z;
    }

  load_lds16(gA0, &As[0][loff0]);
  load_lds16(gA1, &As[0][loff1]);
  load_lds16(gB0, &Bs[0][loff0]);
  load_lds16(gB1, &Bs[0][loff1]);
  __syncthreads();

  for (int it = 0; it < 16; ++it) {
    const int cur = it & 1;
    if (it < 15) {
      const int k1 = (it + 1) * 32;
      const int nxt = cur ^ 1;
      load_lds16(gA0 + k1, &As[nxt][loff0]);
      load_lds16(gA1 + k1, &As[nxt][loff1]);
      load_lds16(gB0 + k1, &Bs[nxt][loff0]);
      load_lds16(gB1 + k1, &Bs[nxt][loff1]);
    }
    bf16x8 af[4], bfr[4];
    #pragma unroll
    for (int i = 0; i < 4; i++) {
      af[i]  = *(const bf16x8*)&As[cur][(wm * 64 + i * 16 + l15) * 32 + quad * 8];
      bfr[i] = *(const bf16x8*)&Bs[cur][(wn * 64 + i * 16 + l15) * 32 + quad * 8];
    }
    #pragma unroll
    for (int i = 0; i < 4; i++)
      #pragma unroll
      for (int j = 0; j < 4; j++)
        acc[i][j] = mfma16(af[i], bfr[j], acc[i][j]);
    __syncthreads();
  }

  #pragma unroll
  for (int i = 0; i < 4; i++) {
    const int row_base = tm * 128 + wm * 64 + i * 16 + quad * 4;
    #pragma unroll
    for (int j = 0; j < 4; j++) {
      const int col = tn * 128 + wn * 64 + j * 16 + l15;
      if (col < Ncols) {
        #pragma unroll
        for (int r = 0; r < 4; r++) {
          int row = row_base + r;
          if (row < M) {
            float v = acc[i][j][r];
            if (OBF16) ((unsigned short*)Cv)[(size_t)row * ldc + col] = f2b(v);
            else       ((float*)Cv)[(size_t)row * ldc + col] = v;
          }
        }
      }
    }
  }
}

// ---- GEMM tile with fp32 A (cvt in staging), bf16 out; Ncols=512, ldc=512 ----
__device__ void gemm_tile_f32A(const float* __restrict__ A, const unsigned short* __restrict__ Bt,
                               unsigned short* __restrict__ C, int M, int tm, int tn)
{
  __shared__ __align__(16) unsigned short As[2][128 * 32];
  __shared__ __align__(16) unsigned short Bs[2][128 * 32];
  const int tid = threadIdx.x;
  const int lane = tid & 63;
  const int wm = (tid >> 6) >> 1;
  const int wn = (tid >> 6) & 1;
  const int quad = lane >> 4, l15 = lane & 15;

  const int r0 = tid >> 2, kc = tid & 3;
  int ga0 = tm * 128 + r0;       if (ga0 > M - 1) ga0 = M - 1;
  int ga1 = tm * 128 + 64 + r0;  if (ga1 > M - 1) ga1 = M - 1;
  const int gb0 = tn * 128 + r0;
  const int gb1 = tn * 128 + 64 + r0;
  const float* gA0 = A + (size_t)ga0 * 512 + kc * 8;
  const float* gA1 = A + (size_t)ga1 * 512 + kc * 8;
  const unsigned short* gB0 = Bt + (size_t)gb0 * 512 + kc * 8;
  const unsigned short* gB1 = Bt + (size_t)gb1 * 512 + kc * 8;
  const int loff0 = r0 * 32 + kc * 8;
  const int loff1 = (64 + r0) * 32 + kc * 8;

  f32x4 acc[4][4];
  #pragma unroll
  for (int i = 0; i < 4; i++)
    #pragma unroll
    for (int j = 0; j < 4; j++) {
      f32x4 z = {0.f, 0.f, 0.f, 0.f};
      acc[i][j] = z;
    }

  {
    float4 a00 = *(const float4*)(gA0), a01 = *(const float4*)(gA0 + 4);
    float4 a10 = *(const float4*)(gA1), a11 = *(const float4*)(gA1 + 4);
    *(uint4*)&As[0][loff0] = cvt8(a00, a01);
    *(uint4*)&As[0][loff1] = cvt8(a10, a11);
    load_lds16(gB0, &Bs[0][loff0]);
    load_lds16(gB1, &Bs[0][loff1]);
  }
  __syncthreads();

  for (int it = 0; it < 16; ++it) {
    const int cur = it & 1, nxt = cur ^ 1;
    float4 a00, a01, a10, a11;
    if (it < 15) {
      const int k1 = (it + 1) * 32;
      a00 = *(const float4*)(gA0 + k1);     a01 = *(const float4*)(gA0 + k1 + 4);
      a10 = *(const float4*)(gA1 + k1);     a11 = *(const float4*)(gA1 + k1 + 4);
      load_lds16(gB0 + k1, &Bs[nxt][loff0]);
      load_lds16(gB1 + k1, &Bs[nxt][loff1]);
    }
    bf16x8 af[4], bfr[4];
    #pragma unroll
    for (int i = 0; i < 4; i++) {
      af[i]  = *(const bf16x8*)&As[cur][(wm * 64 + i * 16 + l15) * 32 + quad * 8];
      bfr[i] = *(const bf16x8*)&Bs[cur][(wn * 64 + i * 16 + l15) * 32 + quad * 8];
    }
    #pragma unroll
    for (int i = 0; i < 4; i++)
      #pragma unroll
      for (int j = 0; j < 4; j++)
        acc[i][j] = mfma16(af[i], bfr[j], acc[i][j]);
    if (it < 15) {
      *(uint4*)&As[nxt][loff0] = cvt8(a00, a01);
      *(uint4*)&As[nxt][loff1] = cvt8(a10, a11);
    }
    __syncthreads();
  }

  #pragma unroll
  for (int i = 0; i < 4; i++) {
    const int row_base = tm * 128 + wm * 64 + i * 16 + quad * 4;
    #pragma unroll
    for (int j = 0; j < 4; j++) {
      const int col = tn * 128 + wn * 64 + j * 16 + l15;
      #pragma unroll
      for (int r = 0; r < 4; r++) {
        int row = row_base + r;
        if (row < M) C[(size_t)row * 512 + col] = f2b(acc[i][j][r]);
      }
    }
  }
}

// ---- LDS-tiled 64x64 transpose: W fp32 [512][ncols] -> Wt bf16 [.][512] ----
__device__ void wtrans_tile(const float* __restrict__ W, unsigned short* __restrict__ Wt,
                            int ncols, int tr0, int tc0)
{
  __shared__ float tile[64][65];
  const int t = threadIdx.x;
  const int r = t >> 2, c4 = t & 3;
  #pragma unroll
  for (int i = 0; i < 4; i++) {
    int col = c4 * 16 + i * 4;
    int gc = tc0 + col;
    float4 v;
    if (gc + 3 < ncols) {
      v = *(const float4*)&W[(size_t)(tr0 + r) * ncols + gc];
    } else {
      v.x = (gc + 0 < ncols) ? W[(size_t)(tr0 + r) * ncols + gc + 0] : 0.f;
      v.y = (gc + 1 < ncols) ? W[(size_t)(tr0 + r) * ncols + gc + 1] : 0.f;
      v.z = (gc + 2 < ncols) ? W[(size_t)(tr0 + r) * ncols + gc + 2] : 0.f;
      v.w = (gc + 3 < ncols) ? W[(size_t)(tr0 + r) * ncols + gc + 3] : 0.f;
    }
    tile[r][col] = v.x; tile[r][col + 1] = v.y;
    tile[r][col + 2] = v.z; tile[r][col + 3] = v.w;
  }
  __syncthreads();
  const int o = t >> 2;
  #pragma unroll
  for (int i = 0; i < 4; i++) {
    int k = c4 * 16 + i * 4;
    ushort4 u;
    u.x = f2b(tile[k + 0][o]); u.y = f2b(tile[k + 1][o]);
    u.z = f2b(tile[k + 2][o]); u.w = f2b(tile[k + 3][o]);
    *(ushort4*)&Wt[(size_t)(tc0 + o) * 512 + tr0 + k] = u;
  }
}

// ================= kernel 1: prep =================
// blocks 0..63: W1 transpose; 64..79: Wc transpose; 80..511: W2->bf16 flat + degree
__global__ __launch_bounds__(256)
void prep(const float* __restrict__ W1, const float* __restrict__ Wc,
          const float* __restrict__ W2, const int* __restrict__ dst,
          int* __restrict__ edeg, unsigned short* __restrict__ W1t,
          unsigned short* __restrict__ Wct, unsigned short* __restrict__ w2b, int E)
{
  if (blockIdx.x < 64) { wtrans_tile(W1, W1t, 512, (blockIdx.x >> 3) * 64, (blockIdx.x & 7) * 64); return; }
  if (blockIdx.x < 80) { int b = blockIdx.x - 64; wtrans_tile(Wc, Wct, 100, (b >> 1) * 64, (b & 1) * 64); return; }
  const int t0 = (blockIdx.x - 80) * 256 + threadIdx.x;
  const int FT = (512 - 80) * 256;
  const float4* W24 = (const float4*)W2;
  uint4* w2b4 = (uint4*)w2b;
  for (int i = t0; i < 512 * 512 / 8; i += FT)
    w2b4[i] = cvt8(W24[i * 2], W24[i * 2 + 1]);
  for (int e = t0; e < E; e += FT) atomicAdd(&edeg[dst[e]], 1);
}

// ================= kernel 2: fillplus = scan + fold + bias2c + gemm1 + CSR fill =================
// blk 0: scan (sets flag); 1..4: W2Wc fold; 5: bias2c; 6..321: gemm1 (fp32 A); 322..478: fill (spin on flag)
__global__ __launch_bounds__(256)
void fillplus(const float* __restrict__ x, const unsigned short* __restrict__ W1t,
              unsigned short* __restrict__ B2,
              const int* __restrict__ src, const int* __restrict__ dst,
              int* __restrict__ edeg, int* __restrict__ rowstart, float* __restrict__ dinv,
              int* __restrict__ csr_src, float* __restrict__ csr_norm,
              int* __restrict__ flag,
              const unsigned short* __restrict__ Wct, const unsigned short* __restrict__ w2b,
              unsigned short* __restrict__ W2WcT,
              const float* __restrict__ b2, const float* __restrict__ Wc,
              const float* __restrict__ bc, float* __restrict__ bias2c, int E)
{
  const int n = NN;
  const int b = blockIdx.x;
  if (b == 0) {
    // exclusive scan -> rowstart, dinv, edeg->0 (cursor), then release flag
    __shared__ int partial[256];
    const int t = threadIdx.x;
    const int per = (n + 255) / 256;
    const int lo = t * per;
    const int hi = (lo + per < n) ? lo + per : n;
    int s = 0;
    for (int i = lo; i < hi; i++) s += edeg[i];
    partial[t] = s;
    __syncthreads();
    for (int off = 1; off < 256; off <<= 1) {
      int v = (t >= off) ? partial[t - off] : 0;
      __syncthreads();
      partial[t] += v;
      __syncthreads();
    }
    int run = (t > 0) ? partial[t - 1] : 0;
    for (int i = lo; i < hi; i++) {
      int d = edeg[i];
      rowstart[i] = run; run += d;
      dinv[i] = rsqrtf(1.0f + (float)d);
      edeg[i] = 0;
    }
    if (t == 255) rowstart[n] = run;
    __syncthreads();
    if (t == 0)
      __hip_atomic_store(flag, 1, __ATOMIC_RELEASE, __HIP_MEMORY_SCOPE_AGENT);
    return;
  }
  if (b <= 4) { gemm_tile<true>(Wct, w2b, W2WcT, 128, 512, 512, 0, b - 1); return; }
  if (b == 5) {
    const int j = threadIdx.x;
    if (j < 128) {
      float s = 0.f;
      if (j < 100) {
        s = bc[j];
        for (int k = 0; k < 512; k++) s = fmaf(b2[k], Wc[k * 100 + j], s);
      }
      bias2c[j] = s;
    }
    return;
  }
  if (b < 6 + 316) {
    const int g = b - 6;
    gemm_tile_f32A(x, W1t, B2, NN, g >> 2, g & 3);
    return;
  }
  // fill blocks: wait for scan
  if (threadIdx.x == 0) {
    int spins = 0;
    while (__hip_atomic_load(flag, __ATOMIC_ACQUIRE, __HIP_MEMORY_SCOPE_AGENT) == 0) {
      __builtin_amdgcn_s_sleep(8);
      if (++spins > 10000000) break;   // bailout: wrong answer beats a hung GPU
    }
  }
  __syncthreads();
  int e = (b - 322) * 256 + threadIdx.x;
  const int stride = 157 * 256;
  for (; e < E; e += stride) {
    int s = src[e], d = dst[e];
    int pos = rowstart[d] + atomicAdd(&edeg[d], 1);
    csr_src[pos] = s;
    csr_norm[pos] = dinv[s] * dinv[d];
  }
}

// ================= kernel 3: gather1, XCD-aware column quarters =================
// quarter = (blockIdx%8)>>1  -> per-XCD working set of h = 2.5 MB (L2-resident)
__global__ __launch_bounds__(256)
void gather1(const unsigned short* __restrict__ h, const float* __restrict__ dinv,
             const int* __restrict__ rowstart, const int* __restrict__ csr_src,
             const float* __restrict__ csr_norm, const float* __restrict__ bias,
             unsigned short* __restrict__ outb, int n)
{
  const int blk = blockIdx.x;             // grid 2560
  const int xcd = blk & 7;
  const int qt = xcd >> 1;                // column quarter 0..3
  const int idx = (blk >> 3) * 2 + (xcd & 1);      // 0..639 within quarter
  const int wv = idx * 4 + (threadIdx.x >> 6);     // 0..2559 within quarter
  const int lane = threadIdx.x & 63;
  const int col = qt * 128 + lane * 2;
  const float2 bb = *(const float2*)&bias[col];

  for (int node = wv; node < n; node += 2560) {
    float di = dinv[node];
    float slf = di * di;
    unsigned int hv = *(const unsigned int*)&h[(size_t)node * 512 + col];
    float a0 = fmaf(b2f((unsigned short)(hv & 0xffffu)), slf, bb.x);
    float a1 = fmaf(b2f((unsigned short)(hv >> 16)),     slf, bb.y);

    const int jb = rowstart[node], je = rowstart[node + 1];
    int j = jb;
    for (; j + 8 <= je; j += 8) {
      int ss[8]; float nm[8]; unsigned int vv[8];
      #pragma unroll
      for (int q = 0; q < 8; q++) { ss[q] = csr_src[j + q]; nm[q] = csr_norm[j + q]; }
      #pragma unroll
      for (int q = 0; q < 8; q++) vv[q] = *(const unsigned int*)&h[(size_t)ss[q] * 512 + col];
      #pragma unroll
      for (int q = 0; q < 8; q++) {
        a0 = fmaf(b2f((unsigned short)(vv[q] & 0xffffu)), nm[q], a0);
        a1 = fmaf(b2f((unsigned short)(vv[q] >> 16)),     nm[q], a1);
      }
    }
    for (; j < je; ++j) {
      unsigned int v = *(const unsigned int*)&h[(size_t)csr_src[j] * 512 + col];
      float nm = csr_norm[j];
      a0 = fmaf(b2f((unsigned short)(v & 0xffffu)), nm, a0);
      a1 = fmaf(b2f((unsigned short)(v >> 16)),     nm, a1);
    }
    a0 = fmaxf(a0, 0.f); a1 = fmaxf(a1, 0.f);
    *(unsigned int*)&outb[(size_t)node * 512 + col] =
        (unsigned int)f2b(a0) | ((unsigned int)f2b(a1) << 16);
  }
}

// ================= kernel 4: gemm2c: C2 = B1 @ W2WcT^T (fp32, 128 cols) =================
__global__ __launch_bounds__(256)
void gemm2c(const unsigned short* __restrict__ B1, const unsigned short* __restrict__ W2WcT,
            float* __restrict__ C2)
{
  gemm_tile<false>(B1, W2WcT, C2, NN, 128, 128, blockIdx.x, 0);
}

// ================= kernel 5: gather2c, XCD-aware column halves =================
// half = (blockIdx%8)>>2 -> per-XCD working set of C2 = 2.5 MB (L2-resident)
__global__ __launch_bounds__(256)
void gather2c(const float* __restrict__ C2, const float* __restrict__ dinv,
              const int* __restrict__ rowstart, const int* __restrict__ csr_src,
              const float* __restrict__ csr_norm, const float* __restrict__ bias2c,
              float* __restrict__ out, int n)
{
  const int blk = blockIdx.x;             // grid 2560
  const int xcd = blk & 7;
  const int hf = xcd >> 2;                // column half 0..1
  const int idx = (blk >> 3) * 4 + (xcd & 3);      // 0..1279 within half
  const int wv = idx * 4 + (threadIdx.x >> 6);     // 0..5119 within half
  const int lane = threadIdx.x & 63;
  const int col = hf * 64 + lane;
  const float bb = bias2c[col];

  for (int node = wv; node < n; node += 5120) {
    float di = dinv[node];
    float slf = di * di;
    float a0 = fmaf(C2[(size_t)node * 128 + col], slf, bb);

    const int jb = rowstart[node], je = rowstart[node + 1];
    int j = jb;
    for (; j + 8 <= je; j += 8) {
      int ss[8]; float nm[8]; float vv[8];
      #pragma unroll
      for (int q = 0; q < 8; q++) { ss[q] = csr_src[j + q]; nm[q] = csr_norm[j + q]; }
      #pragma unroll
      for (int q = 0; q < 8; q++) vv[q] = C2[(size_t)ss[q] * 128 + col];
      #pragma unroll
      for (int q = 0; q < 8; q++) a0 = fmaf(vv[q], nm[q], a0);
    }
    for (; j < je; ++j)
      a0 = fmaf(C2[(size_t)csr_src[j] * 128 + col], csr_norm[j], a0);

    if (col < 100) out[(size_t)node * 100 + col] = a0;
  }
}

extern "C" void kernel_launch(void* const* d_in, const int* in_sizes, int n_in,
                              void* d_out, int out_size, void* d_ws, size_t ws_size,
                              hipStream_t stream) {
  const float* x  = (const float*)d_in[0];
  const int*   ei = (const int*)d_in[1];
  const float* W1 = (const float*)d_in[2];
  const float* b1 = (const float*)d_in[3];
  const float* W2 = (const float*)d_in[4];
  const float* b2 = (const float*)d_in[5];
  const float* Wc = (const float*)d_in[6];
  const float* bc = (const float*)d_in[7];
  float* out = (float*)d_out;

  const int n = NN;
  const int E = in_sizes[1] / 2;
  const int* src = ei;
  const int* dst = ei + E;

  // workspace (~29 MB); flag+edeg first so one memset zeroes both
  char* w = (char*)d_ws;
  int* flag = (int*)w;                      w += 256;
  int* edeg = (int*)w;                      w += ((n * 4 + 255) / 256) * 256;   // also fill cursor
  int* rowstart = (int*)w;                  w += (((n + 1) * 4 + 255) / 256) * 256;
  int* csr_src = (int*)w;                   w += ((E * 4 + 255) / 256) * 256;
  float* csr_norm = (float*)w;              w += ((E * 4 + 255) / 256) * 256;
  float* dinv = (float*)w;                  w += ((n * 4 + 255) / 256) * 256;
  float* bias2c = (float*)w;                w += 512;
  unsigned short* W1t = (unsigned short*)w; w += 512 * 512 * 2;
  unsigned short* Wct = (unsigned short*)w; w += 128 * 512 * 2;
  unsigned short* w2b = (unsigned short*)w; w += 512 * 512 * 2;
  unsigned short* W2WcT = (unsigned short*)w; w += 128 * 512 * 2;
  unsigned short* B1  = (unsigned short*)w; w += (size_t)n * 512 * 2;
  unsigned short* B2  = (unsigned short*)w; w += (size_t)n * 512 * 2;
  float* C2 = (float*)w;                    w += (size_t)n * 128 * 4;

  hipMemsetAsync(flag, 0, 256 + n * sizeof(int), stream);   // flag + edeg
  prep<<<512, 256, 0, stream>>>(W1, Wc, W2, dst, edeg, W1t, Wct, w2b, E);
  fillplus<<<479, 256, 0, stream>>>(x, W1t, B2, src, dst, edeg, rowstart, dinv,
                                    csr_src, csr_norm, flag, Wct, w2b, W2WcT,
                                    b2, Wc, bc, bias2c, E);
  gather1<<<2560, 256, 0, stream>>>(B2, dinv, rowstart, csr_src, csr_norm, b1, B1, n);
  gemm2c<<<79, 256, 0, stream>>>(B1, W2WcT, C2);
  gather2c<<<2560, 256, 0, stream>>>(C2, dinv, rowstart, csr_src, csr_norm, bias2c, out, n);
}

// Round 9
// 206.285 us; speedup vs baseline: 1.7748x; 1.7748x over previous
//
#include <hip/hip_runtime.h>
#include <hip/hip_bf16.h>
#include <stdint.h>

typedef __bf16 bf16_t;
typedef bf16_t bf16x8 __attribute__((ext_vector_type(8)));
typedef float f32x4 __attribute__((ext_vector_type(4)));

#define NN 10000

__device__ __forceinline__ float b2f(unsigned short u) {
  union { unsigned int i; float f; } c; c.i = ((unsigned int)u) << 16; return c.f;
}
__device__ __forceinline__ unsigned short f2b(float f) {
  union { float f; unsigned int i; } c; c.f = f;
  unsigned int x = c.i;
  x += 0x7FFFu + ((x >> 16) & 1u);
  return (unsigned short)(x >> 16);
}
__device__ __forceinline__ uint4 cvt8(float4 a, float4 b) {
  uint4 r;
  r.x = (unsigned int)f2b(a.x) | ((unsigned int)f2b(a.y) << 16);
  r.y = (unsigned int)f2b(a.z) | ((unsigned int)f2b(a.w) << 16);
  r.z = (unsigned int)f2b(b.x) | ((unsigned int)f2b(b.y) << 16);
  r.w = (unsigned int)f2b(b.z) | ((unsigned int)f2b(b.w) << 16);
  return r;
}
__device__ __forceinline__ void load_lds16(const void* g, void* l) {
  __builtin_amdgcn_global_load_lds(
      (const __attribute__((address_space(1))) unsigned int*)g,
      (__attribute__((address_space(3))) unsigned int*)l, 16, 0, 0);
}
__device__ __forceinline__ f32x4 mfma16(bf16x8 a, bf16x8 b, f32x4 c) {
  return __builtin_amdgcn_mfma_f32_16x16x32_bf16(a, b, c, 0, 0, 0);
}

// ---- GEMM tile (bf16 A via global_load_lds): C[128x128] @ (tm,tn) ----
template <bool OBF16>
__device__ void gemm_tile(const unsigned short* __restrict__ A, const unsigned short* __restrict__ Bt,
                          void* __restrict__ Cv, int M, int Ncols, int ldc, int tm, int tn)
{
  __shared__ __align__(16) unsigned short As[2][128 * 32];
  __shared__ __align__(16) unsigned short Bs[2][128 * 32];
  const int tid = threadIdx.x;
  const int lane = tid & 63;
  const int wm = (tid >> 6) >> 1;
  const int wn = (tid >> 6) & 1;
  const int quad = lane >> 4, l15 = lane & 15;

  const int r0 = tid >> 2, kc = tid & 3;
  int ga0 = tm * 128 + r0;       if (ga0 > M - 1) ga0 = M - 1;
  int ga1 = tm * 128 + 64 + r0;  if (ga1 > M - 1) ga1 = M - 1;
  const int gb0 = tn * 128 + r0;
  const int gb1 = tn * 128 + 64 + r0;
  const unsigned short* gA0 = A + (size_t)ga0 * 512 + kc * 8;
  const unsigned short* gA1 = A + (size_t)ga1 * 512 + kc * 8;
  const unsigned short* gB0 = Bt + (size_t)gb0 * 512 + kc * 8;
  const unsigned short* gB1 = Bt + (size_t)gb1 * 512 + kc * 8;
  const int loff0 = r0 * 32 + kc * 8;
  const int loff1 = (64 + r0) * 32 + kc * 8;

  f32x4 acc[4][4];
  #pragma unroll
  for (int i = 0; i < 4; i++)
    #pragma unroll
    for (int j = 0; j < 4; j++) {
      f32x4 z = {0.f, 0.f, 0.f, 0.f};
      acc[i][j] = z;
    }

  load_lds16(gA0, &As[0][loff0]);
  load_lds16(gA1, &As[0][loff1]);
  load_lds16(gB0, &Bs[0][loff0]);
  load_lds16(gB1, &Bs[0][loff1]);
  __syncthreads();

  for (int it = 0; it < 16; ++it) {
    const int cur = it & 1;
    if (it < 15) {
      const int k1 = (it + 1) * 32;
      const int nxt = cur ^ 1;
      load_lds16(gA0 + k1, &As[nxt][loff0]);
      load_lds16(gA1 + k1, &As[nxt][loff1]);
      load_lds16(gB0 + k1, &Bs[nxt][loff0]);
      load_lds16(gB1 + k1, &Bs[nxt][loff1]);
    }
    bf16x8 af[4], bfr[4];
    #pragma unroll
    for (int i = 0; i < 4; i++) {
      af[i]  = *(const bf16x8*)&As[cur][(wm * 64 + i * 16 + l15) * 32 + quad * 8];
      bfr[i] = *(const bf16x8*)&Bs[cur][(wn * 64 + i * 16 + l15) * 32 + quad * 8];
    }
    #pragma unroll
    for (int i = 0; i < 4; i++)
      #pragma unroll
      for (int j = 0; j < 4; j++)
        acc[i][j] = mfma16(af[i], bfr[j], acc[i][j]);
    __syncthreads();
  }

  #pragma unroll
  for (int i = 0; i < 4; i++) {
    const int row_base = tm * 128 + wm * 64 + i * 16 + quad * 4;
    #pragma unroll
    for (int j = 0; j < 4; j++) {
      const int col = tn * 128 + wn * 64 + j * 16 + l15;
      if (col < Ncols) {
        #pragma unroll
        for (int r = 0; r < 4; r++) {
          int row = row_base + r;
          if (row < M) {
            float v = acc[i][j][r];
            if (OBF16) ((unsigned short*)Cv)[(size_t)row * ldc + col] = f2b(v);
            else       ((float*)Cv)[(size_t)row * ldc + col] = v;
          }
        }
      }
    }
  }
}

// ---- GEMM tile with fp32 A (cvt in staging), bf16 out; Ncols=512, ldc=512 ----
__device__ void gemm_tile_f32A(const float* __restrict__ A, const unsigned short* __restrict__ Bt,
                               unsigned short* __restrict__ C, int M, int tm, int tn)
{
  __shared__ __align__(16) unsigned short As[2][128 * 32];
  __shared__ __align__(16) unsigned short Bs[2][128 * 32];
  const int tid = threadIdx.x;
  const int lane = tid & 63;
  const int wm = (tid >> 6) >> 1;
  const int wn = (tid >> 6) & 1;
  const int quad = lane >> 4, l15 = lane & 15;

  const int r0 = tid >> 2, kc = tid & 3;
  int ga0 = tm * 128 + r0;       if (ga0 > M - 1) ga0 = M - 1;
  int ga1 = tm * 128 + 64 + r0;  if (ga1 > M - 1) ga1 = M - 1;
  const int gb0 = tn * 128 + r0;
  const int gb1 = tn * 128 + 64 + r0;
  const float* gA0 = A + (size_t)ga0 * 512 + kc * 8;
  const float* gA1 = A + (size_t)ga1 * 512 + kc * 8;
  const unsigned short* gB0 = Bt + (size_t)gb0 * 512 + kc * 8;
  const unsigned short* gB1 = Bt + (size_t)gb1 * 512 + kc * 8;
  const int loff0 = r0 * 32 + kc * 8;
  const int loff1 = (64 + r0) * 32 + kc * 8;

  f32x4 acc[4][4];
  #pragma unroll
  for (int i = 0; i < 4; i++)
    #pragma unroll
    for (int j = 0; j < 4; j++) {
      f32x4 z = {0.f, 0.f, 0.f, 0.f};
      acc[i][j] = z;
    }

  {
    float4 a00 = *(const float4*)(gA0), a01 = *(const float4*)(gA0 + 4);
    float4 a10 = *(const float4*)(gA1), a11 = *(const float4*)(gA1 + 4);
    *(uint4*)&As[0][loff0] = cvt8(a00, a01);
    *(uint4*)&As[0][loff1] = cvt8(a10, a11);
    load_lds16(gB0, &Bs[0][loff0]);
    load_lds16(gB1, &Bs[0][loff1]);
  }
  __syncthreads();

  for (int it = 0; it < 16; ++it) {
    const int cur = it & 1, nxt = cur ^ 1;
    float4 a00, a01, a10, a11;
    if (it < 15) {
      const int k1 = (it + 1) * 32;
      a00 = *(const float4*)(gA0 + k1);     a01 = *(const float4*)(gA0 + k1 + 4);
      a10 = *(const float4*)(gA1 + k1);     a11 = *(const float4*)(gA1 + k1 + 4);
      load_lds16(gB0 + k1, &Bs[nxt][loff0]);
      load_lds16(gB1 + k1, &Bs[nxt][loff1]);
    }
    bf16x8 af[4], bfr[4];
    #pragma unroll
    for (int i = 0; i < 4; i++) {
      af[i]  = *(const bf16x8*)&As[cur][(wm * 64 + i * 16 + l15) * 32 + quad * 8];
      bfr[i] = *(const bf16x8*)&Bs[cur][(wn * 64 + i * 16 + l15) * 32 + quad * 8];
    }
    #pragma unroll
    for (int i = 0; i < 4; i++)
      #pragma unroll
      for (int j = 0; j < 4; j++)
        acc[i][j] = mfma16(af[i], bfr[j], acc[i][j]);
    if (it < 15) {
      *(uint4*)&As[nxt][loff0] = cvt8(a00, a01);
      *(uint4*)&As[nxt][loff1] = cvt8(a10, a11);
    }
    __syncthreads();
  }

  #pragma unroll
  for (int i = 0; i < 4; i++) {
    const int row_base = tm * 128 + wm * 64 + i * 16 + quad * 4;
    #pragma unroll
    for (int j = 0; j < 4; j++) {
      const int col = tn * 128 + wn * 64 + j * 16 + l15;
      #pragma unroll
      for (int r = 0; r < 4; r++) {
        int row = row_base + r;
        if (row < M) C[(size_t)row * 512 + col] = f2b(acc[i][j][r]);
      }
    }
  }
}

// ---- LDS-tiled 64x64 transpose: W fp32 [512][ncols] -> Wt bf16 [.][512] ----
__device__ void wtrans_tile(const float* __restrict__ W, unsigned short* __restrict__ Wt,
                            int ncols, int tr0, int tc0)
{
  __shared__ float tile[64][65];
  const int t = threadIdx.x;
  const int r = t >> 2, c4 = t & 3;
  #pragma unroll
  for (int i = 0; i < 4; i++) {
    int col = c4 * 16 + i * 4;
    int gc = tc0 + col;
    float4 v;
    if (gc + 3 < ncols) {
      v = *(const float4*)&W[(size_t)(tr0 + r) * ncols + gc];
    } else {
      v.x = (gc + 0 < ncols) ? W[(size_t)(tr0 + r) * ncols + gc + 0] : 0.f;
      v.y = (gc + 1 < ncols) ? W[(size_t)(tr0 + r) * ncols + gc + 1] : 0.f;
      v.z = (gc + 2 < ncols) ? W[(size_t)(tr0 + r) * ncols + gc + 2] : 0.f;
      v.w = (gc + 3 < ncols) ? W[(size_t)(tr0 + r) * ncols + gc + 3] : 0.f;
    }
    tile[r][col] = v.x; tile[r][col + 1] = v.y;
    tile[r][col + 2] = v.z; tile[r][col + 3] = v.w;
  }
  __syncthreads();
  const int o = t >> 2;
  #pragma unroll
  for (int i = 0; i < 4; i++) {
    int k = c4 * 16 + i * 4;
    ushort4 u;
    u.x = f2b(tile[k + 0][o]); u.y = f2b(tile[k + 1][o]);
    u.z = f2b(tile[k + 2][o]); u.w = f2b(tile[k + 3][o]);
    *(ushort4*)&Wt[(size_t)(tc0 + o) * 512 + tr0 + k] = u;
  }
}

// ================= kernel 1: prep =================
// blocks 0..63: W1 transpose; 64..79: Wc transpose; 80..511: W2->bf16 flat + degree
__global__ __launch_bounds__(256)
void prep(const float* __restrict__ W1, const float* __restrict__ Wc,
          const float* __restrict__ W2, const int* __restrict__ dst,
          int* __restrict__ edeg, unsigned short* __restrict__ W1t,
          unsigned short* __restrict__ Wct, unsigned short* __restrict__ w2b, int E)
{
  if (blockIdx.x < 64) { wtrans_tile(W1, W1t, 512, (blockIdx.x >> 3) * 64, (blockIdx.x & 7) * 64); return; }
  if (blockIdx.x < 80) { int b = blockIdx.x - 64; wtrans_tile(Wc, Wct, 100, (b >> 1) * 64, (b & 1) * 64); return; }
  const int t0 = (blockIdx.x - 80) * 256 + threadIdx.x;
  const int FT = (512 - 80) * 256;
  const float4* W24 = (const float4*)W2;
  uint4* w2b4 = (uint4*)w2b;
  for (int i = t0; i < 512 * 512 / 8; i += FT)
    w2b4[i] = cvt8(W24[i * 2], W24[i * 2 + 1]);
  for (int e = t0; e < E; e += FT) atomicAdd(&edeg[dst[e]], 1);
}

// ================= kernel 2: scan_plus (grid=6, no cross-block sync) =================
// blk 0: scan -> rowstart, dinv, edeg->0 (cursor); 1..4: W2Wc fold; 5: bias2c
__global__ __launch_bounds__(256)
void scan_plus(int* __restrict__ edeg, int* __restrict__ rowstart, float* __restrict__ dinv,
               const unsigned short* __restrict__ Wct, const unsigned short* __restrict__ w2b,
               unsigned short* __restrict__ W2WcT,
               const float* __restrict__ b2, const float* __restrict__ Wc,
               const float* __restrict__ bc, float* __restrict__ bias2c, int n)
{
  if (blockIdx.x == 0) {
    __shared__ int partial[256];
    const int t = threadIdx.x;
    const int per = (n + 255) / 256;
    const int lo = t * per;
    const int hi = (lo + per < n) ? lo + per : n;
    int s = 0;
    for (int i = lo; i < hi; i++) s += edeg[i];
    partial[t] = s;
    __syncthreads();
    for (int off = 1; off < 256; off <<= 1) {
      int v = (t >= off) ? partial[t - off] : 0;
      __syncthreads();
      partial[t] += v;
      __syncthreads();
    }
    int run = (t > 0) ? partial[t - 1] : 0;
    for (int i = lo; i < hi; i++) {
      int d = edeg[i];
      rowstart[i] = run; run += d;
      dinv[i] = rsqrtf(1.0f + (float)d);
      edeg[i] = 0;
    }
    if (t == 255) rowstart[n] = run;
  } else if (blockIdx.x <= 4) {
    gemm_tile<true>(Wct, w2b, W2WcT, 128, 512, 512, 0, blockIdx.x - 1);
  } else {
    const int j = threadIdx.x;
    if (j < 128) {
      float s = 0.f;
      if (j < 100) {
        s = bc[j];
        for (int k = 0; k < 512; k++) s = fmaf(b2[k], Wc[k * 100 + j], s);
      }
      bias2c[j] = s;
    }
  }
}

// ================= kernel 3: gemm1 (fp32 A) + CSR fill (role-split, no sync) =================
__global__ __launch_bounds__(256)
void fill_gemm1(const float* __restrict__ x, const unsigned short* __restrict__ W1t,
                unsigned short* __restrict__ B2,
                const int* __restrict__ src, const int* __restrict__ dst,
                const float* __restrict__ dinv, const int* __restrict__ rowstart,
                int* __restrict__ cursor, int* __restrict__ csr_src,
                float* __restrict__ csr_norm, int E)
{
  if (blockIdx.x < 316) {   // 79 x 4 tiles of 10000x512
    gemm_tile_f32A(x, W1t, B2, NN, blockIdx.x >> 2, blockIdx.x & 3);
  } else {
    int e = (blockIdx.x - 316) * 256 + threadIdx.x;
    const int stride = 157 * 256;
    for (; e < E; e += stride) {
      int s = src[e], d = dst[e];
      int pos = rowstart[d] + atomicAdd(&cursor[d], 1);
      csr_src[pos] = s;
      csr_norm[pos] = dinv[s] * dinv[d];
    }
  }
}

// ================= kernel 4: gather1, XCD-aware column quarters =================
__global__ __launch_bounds__(256)
void gather1(const unsigned short* __restrict__ h, const float* __restrict__ dinv,
             const int* __restrict__ rowstart, const int* __restrict__ csr_src,
             const float* __restrict__ csr_norm, const float* __restrict__ bias,
             unsigned short* __restrict__ outb, int n)
{
  const int blk = blockIdx.x;             // grid 2560
  const int xcd = blk & 7;
  const int qt = xcd >> 1;                // column quarter 0..3
  const int idx = (blk >> 3) * 2 + (xcd & 1);      // 0..639 within quarter
  const int wv = idx * 4 + (threadIdx.x >> 6);     // 0..2559 within quarter
  const int lane = threadIdx.x & 63;
  const int col = qt * 128 + lane * 2;
  const float2 bb = *(const float2*)&bias[col];

  for (int node = wv; node < n; node += 2560) {
    float di = dinv[node];
    float slf = di * di;
    unsigned int hv = *(const unsigned int*)&h[(size_t)node * 512 + col];
    float a0 = fmaf(b2f((unsigned short)(hv & 0xffffu)), slf, bb.x);
    float a1 = fmaf(b2f((unsigned short)(hv >> 16)),     slf, bb.y);

    const int jb = rowstart[node], je = rowstart[node + 1];
    int j = jb;
    for (; j + 8 <= je; j += 8) {
      int ss[8]; float nm[8]; unsigned int vv[8];
      #pragma unroll
      for (int q = 0; q < 8; q++) { ss[q] = csr_src[j + q]; nm[q] = csr_norm[j + q]; }
      #pragma unroll
      for (int q = 0; q < 8; q++) vv[q] = *(const unsigned int*)&h[(size_t)ss[q] * 512 + col];
      #pragma unroll
      for (int q = 0; q < 8; q++) {
        a0 = fmaf(b2f((unsigned short)(vv[q] & 0xffffu)), nm[q], a0);
        a1 = fmaf(b2f((unsigned short)(vv[q] >> 16)),     nm[q], a1);
      }
    }
    for (; j < je; ++j) {
      unsigned int v = *(const unsigned int*)&h[(size_t)csr_src[j] * 512 + col];
      float nm = csr_norm[j];
      a0 = fmaf(b2f((unsigned short)(v & 0xffffu)), nm, a0);
      a1 = fmaf(b2f((unsigned short)(v >> 16)),     nm, a1);
    }
    a0 = fmaxf(a0, 0.f); a1 = fmaxf(a1, 0.f);
    *(unsigned int*)&outb[(size_t)node * 512 + col] =
        (unsigned int)f2b(a0) | ((unsigned int)f2b(a1) << 16);
  }
}

// ================= kernel 5: gemm2c: C2 = B1 @ W2WcT^T (fp32, 128 cols) =================
__global__ __launch_bounds__(256)
void gemm2c(const unsigned short* __restrict__ B1, const unsigned short* __restrict__ W2WcT,
            float* __restrict__ C2)
{
  gemm_tile<false>(B1, W2WcT, C2, NN, 128, 128, blockIdx.x, 0);
}

// ================= kernel 6: gather2c, XCD-aware column halves =================
__global__ __launch_bounds__(256)
void gather2c(const float* __restrict__ C2, const float* __restrict__ dinv,
              const int* __restrict__ rowstart, const int* __restrict__ csr_src,
              const float* __restrict__ csr_norm, const float* __restrict__ bias2c,
              float* __restrict__ out, int n)
{
  const int blk = blockIdx.x;             // grid 2560
  const int xcd = blk & 7;
  const int hf = xcd >> 2;                // column half 0..1
  const int idx = (blk >> 3) * 4 + (xcd & 3);      // 0..1279 within half
  const int wv = idx * 4 + (threadIdx.x >> 6);     // 0..5119 within half
  const int lane = threadIdx.x & 63;
  const int col = hf * 64 + lane;
  const float bb = bias2c[col];

  for (int node = wv; node < n; node += 5120) {
    float di = dinv[node];
    float slf = di * di;
    float a0 = fmaf(C2[(size_t)node * 128 + col], slf, bb);

    const int jb = rowstart[node], je = rowstart[node + 1];
    int j = jb;
    for (; j + 8 <= je; j += 8) {
      int ss[8]; float nm[8]; float vv[8];
      #pragma unroll
      for (int q = 0; q < 8; q++) { ss[q] = csr_src[j + q]; nm[q] = csr_norm[j + q]; }
      #pragma unroll
      for (int q = 0; q < 8; q++) vv[q] = C2[(size_t)ss[q] * 128 + col];
      #pragma unroll
      for (int q = 0; q < 8; q++) a0 = fmaf(vv[q], nm[q], a0);
    }
    for (; j < je; ++j)
      a0 = fmaf(C2[(size_t)csr_src[j] * 128 + col], csr_norm[j], a0);

    if (col < 100) out[(size_t)node * 100 + col] = a0;
  }
}

extern "C" void kernel_launch(void* const* d_in, const int* in_sizes, int n_in,
                              void* d_out, int out_size, void* d_ws, size_t ws_size,
                              hipStream_t stream) {
  const float* x  = (const float*)d_in[0];
  const int*   ei = (const int*)d_in[1];
  const float* W1 = (const float*)d_in[2];
  const float* b1 = (const float*)d_in[3];
  const float* W2 = (const float*)d_in[4];
  const float* b2 = (const float*)d_in[5];
  const float* Wc = (const float*)d_in[6];
  const float* bc = (const float*)d_in[7];
  float* out = (float*)d_out;

  const int n = NN;
  const int E = in_sizes[1] / 2;
  const int* src = ei;
  const int* dst = ei + E;

  // workspace (~29 MB)
  char* w = (char*)d_ws;
  int* edeg = (int*)w;                      w += ((n * 4 + 255) / 256) * 256;   // also fill cursor
  int* rowstart = (int*)w;                  w += (((n + 1) * 4 + 255) / 256) * 256;
  int* csr_src = (int*)w;                   w += ((E * 4 + 255) / 256) * 256;
  float* csr_norm = (float*)w;              w += ((E * 4 + 255) / 256) * 256;
  float* dinv = (float*)w;                  w += ((n * 4 + 255) / 256) * 256;
  float* bias2c = (float*)w;                w += 512;
  unsigned short* W1t = (unsigned short*)w; w += 512 * 512 * 2;
  unsigned short* Wct = (unsigned short*)w; w += 128 * 512 * 2;
  unsigned short* w2b = (unsigned short*)w; w += 512 * 512 * 2;
  unsigned short* W2WcT = (unsigned short*)w; w += 128 * 512 * 2;
  unsigned short* B1  = (unsigned short*)w; w += (size_t)n * 512 * 2;
  unsigned short* B2  = (unsigned short*)w; w += (size_t)n * 512 * 2;
  float* C2 = (float*)w;                    w += (size_t)n * 128 * 4;

  hipMemsetAsync(edeg, 0, n * sizeof(int), stream);
  prep<<<512, 256, 0, stream>>>(W1, Wc, W2, dst, edeg, W1t, Wct, w2b, E);
  scan_plus<<<6, 256, 0, stream>>>(edeg, rowstart, dinv, Wct, w2b, W2WcT, b2, Wc, bc, bias2c, n);
  fill_gemm1<<<316 + 157, 256, 0, stream>>>(x, W1t, B2, src, dst, dinv, rowstart,
                                            edeg, csr_src, csr_norm, E);
  gather1<<<2560, 256, 0, stream>>>(B2, dinv, rowstart, csr_src, csr_norm, b1, B1, n);
  gemm2c<<<79, 256, 0, stream>>>(B1, W2WcT, C2);
  gather2c<<<2560, 256, 0, stream>>>(C2, dinv, rowstart, csr_src, csr_norm, bias2c, out, n);
}

// Round 10
// 191.766 us; speedup vs baseline: 1.9092x; 1.0757x over previous
//
#include <hip/hip_runtime.h>
#include <hip/hip_bf16.h>
#include <stdint.h>

typedef __bf16 bf16_t;
typedef bf16_t bf16x8 __attribute__((ext_vector_type(8)));
typedef float f32x4 __attribute__((ext_vector_type(4)));

#define NN 10000

__device__ __forceinline__ float b2f(unsigned short u) {
  union { unsigned int i; float f; } c; c.i = ((unsigned int)u) << 16; return c.f;
}
__device__ __forceinline__ unsigned short f2b(float f) {
  union { float f; unsigned int i; } c; c.f = f;
  unsigned int x = c.i;
  x += 0x7FFFu + ((x >> 16) & 1u);
  return (unsigned short)(x >> 16);
}
__device__ __forceinline__ uint4 cvt8(float4 a, float4 b) {
  uint4 r;
  r.x = (unsigned int)f2b(a.x) | ((unsigned int)f2b(a.y) << 16);
  r.y = (unsigned int)f2b(a.z) | ((unsigned int)f2b(a.w) << 16);
  r.z = (unsigned int)f2b(b.x) | ((unsigned int)f2b(b.y) << 16);
  r.w = (unsigned int)f2b(b.z) | ((unsigned int)f2b(b.w) << 16);
  return r;
}
__device__ __forceinline__ void load_lds16(const void* g, void* l) {
  __builtin_amdgcn_global_load_lds(
      (const __attribute__((address_space(1))) unsigned int*)g,
      (__attribute__((address_space(3))) unsigned int*)l, 16, 0, 0);
}
__device__ __forceinline__ f32x4 mfma16(bf16x8 a, bf16x8 b, f32x4 c) {
  return __builtin_amdgcn_mfma_f32_16x16x32_bf16(a, b, c, 0, 0, 0);
}

// ---- GEMM tile (bf16 A via global_load_lds): C[128x128] @ (tm,tn) ----
template <bool OBF16>
__device__ void gemm_tile(const unsigned short* __restrict__ A, const unsigned short* __restrict__ Bt,
                          void* __restrict__ Cv, int M, int Ncols, int ldc, int tm, int tn)
{
  __shared__ __align__(16) unsigned short As[2][128 * 32];
  __shared__ __align__(16) unsigned short Bs[2][128 * 32];
  const int tid = threadIdx.x;
  const int lane = tid & 63;
  const int wm = (tid >> 6) >> 1;
  const int wn = (tid >> 6) & 1;
  const int quad = lane >> 4, l15 = lane & 15;

  const int r0 = tid >> 2, kc = tid & 3;
  int ga0 = tm * 128 + r0;       if (ga0 > M - 1) ga0 = M - 1;
  int ga1 = tm * 128 + 64 + r0;  if (ga1 > M - 1) ga1 = M - 1;
  const int gb0 = tn * 128 + r0;
  const int gb1 = tn * 128 + 64 + r0;
  const unsigned short* gA0 = A + (size_t)ga0 * 512 + kc * 8;
  const unsigned short* gA1 = A + (size_t)ga1 * 512 + kc * 8;
  const unsigned short* gB0 = Bt + (size_t)gb0 * 512 + kc * 8;
  const unsigned short* gB1 = Bt + (size_t)gb1 * 512 + kc * 8;
  const int loff0 = r0 * 32 + kc * 8;
  const int loff1 = (64 + r0) * 32 + kc * 8;

  f32x4 acc[4][4];
  #pragma unroll
  for (int i = 0; i < 4; i++)
    #pragma unroll
    for (int j = 0; j < 4; j++) {
      f32x4 z = {0.f, 0.f, 0.f, 0.f};
      acc[i][j] = z;
    }

  load_lds16(gA0, &As[0][loff0]);
  load_lds16(gA1, &As[0][loff1]);
  load_lds16(gB0, &Bs[0][loff0]);
  load_lds16(gB1, &Bs[0][loff1]);
  __syncthreads();

  for (int it = 0; it < 16; ++it) {
    const int cur = it & 1;
    if (it < 15) {
      const int k1 = (it + 1) * 32;
      const int nxt = cur ^ 1;
      load_lds16(gA0 + k1, &As[nxt][loff0]);
      load_lds16(gA1 + k1, &As[nxt][loff1]);
      load_lds16(gB0 + k1, &Bs[nxt][loff0]);
      load_lds16(gB1 + k1, &Bs[nxt][loff1]);
    }
    bf16x8 af[4], bfr[4];
    #pragma unroll
    for (int i = 0; i < 4; i++) {
      af[i]  = *(const bf16x8*)&As[cur][(wm * 64 + i * 16 + l15) * 32 + quad * 8];
      bfr[i] = *(const bf16x8*)&Bs[cur][(wn * 64 + i * 16 + l15) * 32 + quad * 8];
    }
    #pragma unroll
    for (int i = 0; i < 4; i++)
      #pragma unroll
      for (int j = 0; j < 4; j++)
        acc[i][j] = mfma16(af[i], bfr[j], acc[i][j]);
    __syncthreads();
  }

  #pragma unroll
  for (int i = 0; i < 4; i++) {
    const int row_base = tm * 128 + wm * 64 + i * 16 + quad * 4;
    #pragma unroll
    for (int j = 0; j < 4; j++) {
      const int col = tn * 128 + wn * 64 + j * 16 + l15;
      if (col < Ncols) {
        #pragma unroll
        for (int r = 0; r < 4; r++) {
          int row = row_base + r;
          if (row < M) {
            float v = acc[i][j][r];
            if (OBF16) ((unsigned short*)Cv)[(size_t)row * ldc + col] = f2b(v);
            else       ((float*)Cv)[(size_t)row * ldc + col] = v;
          }
        }
      }
    }
  }
}

// ---- GEMM tile with fp32 A (cvt in staging), bf16 out; Ncols=512, ldc=512 ----
__device__ void gemm_tile_f32A(const float* __restrict__ A, const unsigned short* __restrict__ Bt,
                               unsigned short* __restrict__ C, int M, int tm, int tn)
{
  __shared__ __align__(16) unsigned short As[2][128 * 32];
  __shared__ __align__(16) unsigned short Bs[2][128 * 32];
  const int tid = threadIdx.x;
  const int lane = tid & 63;
  const int wm = (tid >> 6) >> 1;
  const int wn = (tid >> 6) & 1;
  const int quad = lane >> 4, l15 = lane & 15;

  const int r0 = tid >> 2, kc = tid & 3;
  int ga0 = tm * 128 + r0;       if (ga0 > M - 1) ga0 = M - 1;
  int ga1 = tm * 128 + 64 + r0;  if (ga1 > M - 1) ga1 = M - 1;
  const int gb0 = tn * 128 + r0;
  const int gb1 = tn * 128 + 64 + r0;
  const float* gA0 = A + (size_t)ga0 * 512 + kc * 8;
  const float* gA1 = A + (size_t)ga1 * 512 + kc * 8;
  const unsigned short* gB0 = Bt + (size_t)gb0 * 512 + kc * 8;
  const unsigned short* gB1 = Bt + (size_t)gb1 * 512 + kc * 8;
  const int loff0 = r0 * 32 + kc * 8;
  const int loff1 = (64 + r0) * 32 + kc * 8;

  f32x4 acc[4][4];
  #pragma unroll
  for (int i = 0; i < 4; i++)
    #pragma unroll
    for (int j = 0; j < 4; j++) {
      f32x4 z = {0.f, 0.f, 0.f, 0.f};
      acc[i][j] = z;
    }

  {
    float4 a00 = *(const float4*)(gA0), a01 = *(const float4*)(gA0 + 4);
    float4 a10 = *(const float4*)(gA1), a11 = *(const float4*)(gA1 + 4);
    *(uint4*)&As[0][loff0] = cvt8(a00, a01);
    *(uint4*)&As[0][loff1] = cvt8(a10, a11);
    load_lds16(gB0, &Bs[0][loff0]);
    load_lds16(gB1, &Bs[0][loff1]);
  }
  __syncthreads();

  for (int it = 0; it < 16; ++it) {
    const int cur = it & 1, nxt = cur ^ 1;
    float4 a00, a01, a10, a11;
    if (it < 15) {
      const int k1 = (it + 1) * 32;
      a00 = *(const float4*)(gA0 + k1);     a01 = *(const float4*)(gA0 + k1 + 4);
      a10 = *(const float4*)(gA1 + k1);     a11 = *(const float4*)(gA1 + k1 + 4);
      load_lds16(gB0 + k1, &Bs[nxt][loff0]);
      load_lds16(gB1 + k1, &Bs[nxt][loff1]);
    }
    bf16x8 af[4], bfr[4];
    #pragma unroll
    for (int i = 0; i < 4; i++) {
      af[i]  = *(const bf16x8*)&As[cur][(wm * 64 + i * 16 + l15) * 32 + quad * 8];
      bfr[i] = *(const bf16x8*)&Bs[cur][(wn * 64 + i * 16 + l15) * 32 + quad * 8];
    }
    #pragma unroll
    for (int i = 0; i < 4; i++)
      #pragma unroll
      for (int j = 0; j < 4; j++)
        acc[i][j] = mfma16(af[i], bfr[j], acc[i][j]);
    if (it < 15) {
      *(uint4*)&As[nxt][loff0] = cvt8(a00, a01);
      *(uint4*)&As[nxt][loff1] = cvt8(a10, a11);
    }
    __syncthreads();
  }

  #pragma unroll
  for (int i = 0; i < 4; i++) {
    const int row_base = tm * 128 + wm * 64 + i * 16 + quad * 4;
    #pragma unroll
    for (int j = 0; j < 4; j++) {
      const int col = tn * 128 + wn * 64 + j * 16 + l15;
      #pragma unroll
      for (int r = 0; r < 4; r++) {
        int row = row_base + r;
        if (row < M) C[(size_t)row * 512 + col] = f2b(acc[i][j][r]);
      }
    }
  }
}

// ---- LDS-tiled 64x64 transpose: W fp32 [512][ncols] -> Wt bf16 [.][512] ----
__device__ void wtrans_tile(const float* __restrict__ W, unsigned short* __restrict__ Wt,
                            int ncols, int tr0, int tc0)
{
  __shared__ float tile[64][65];
  const int t = threadIdx.x;
  const int r = t >> 2, c4 = t & 3;
  #pragma unroll
  for (int i = 0; i < 4; i++) {
    int col = c4 * 16 + i * 4;
    int gc = tc0 + col;
    float4 v;
    if (gc + 3 < ncols) {
      v = *(const float4*)&W[(size_t)(tr0 + r) * ncols + gc];
    } else {
      v.x = (gc + 0 < ncols) ? W[(size_t)(tr0 + r) * ncols + gc + 0] : 0.f;
      v.y = (gc + 1 < ncols) ? W[(size_t)(tr0 + r) * ncols + gc + 1] : 0.f;
      v.z = (gc + 2 < ncols) ? W[(size_t)(tr0 + r) * ncols + gc + 2] : 0.f;
      v.w = (gc + 3 < ncols) ? W[(size_t)(tr0 + r) * ncols + gc + 3] : 0.f;
    }
    tile[r][col] = v.x; tile[r][col + 1] = v.y;
    tile[r][col + 2] = v.z; tile[r][col + 3] = v.w;
  }
  __syncthreads();
  const int o = t >> 2;
  #pragma unroll
  for (int i = 0; i < 4; i++) {
    int k = c4 * 16 + i * 4;
    ushort4 u;
    u.x = f2b(tile[k + 0][o]); u.y = f2b(tile[k + 1][o]);
    u.z = f2b(tile[k + 2][o]); u.w = f2b(tile[k + 3][o]);
    *(ushort4*)&Wt[(size_t)(tc0 + o) * 512 + tr0 + k] = u;
  }
}

// ================= kernel 1: prep =================
// 0..63: W1 transpose; 64..79: Wc transpose; 80..511: W2->bf16 flat + degree
__global__ __launch_bounds__(256)
void prep(const float* __restrict__ W1, const float* __restrict__ Wc,
          const float* __restrict__ W2, const int* __restrict__ dst,
          int* __restrict__ edeg, unsigned short* __restrict__ W1t,
          unsigned short* __restrict__ Wct, unsigned short* __restrict__ w2b, int E)
{
  if (blockIdx.x < 64) { wtrans_tile(W1, W1t, 512, (blockIdx.x >> 3) * 64, (blockIdx.x & 7) * 64); return; }
  if (blockIdx.x < 80) { int b = blockIdx.x - 64; wtrans_tile(Wc, Wct, 100, (b >> 1) * 64, (b & 1) * 64); return; }
  const int t0 = (blockIdx.x - 80) * 256 + threadIdx.x;
  const int FT = (512 - 80) * 256;
  const float4* W24 = (const float4*)W2;
  uint4* w2b4 = (uint4*)w2b;
  for (int i = t0; i < 512 * 512 / 8; i += FT)
    w2b4[i] = cvt8(W24[i * 2], W24[i * 2 + 1]);
  for (int e = t0; e < E; e += FT) atomicAdd(&edeg[dst[e]], 1);
}

// ================= kernel 2: scan_plus (grid=6) =================
__global__ __launch_bounds__(256)
void scan_plus(int* __restrict__ edeg, int* __restrict__ rowstart, float* __restrict__ dinv,
               const unsigned short* __restrict__ Wct, const unsigned short* __restrict__ w2b,
               unsigned short* __restrict__ W2WcT,
               const float* __restrict__ b2, const float* __restrict__ Wc,
               const float* __restrict__ bc, float* __restrict__ bias2c, int n)
{
  if (blockIdx.x == 0) {
    __shared__ int partial[256];
    const int t = threadIdx.x;
    const int per = (n + 255) / 256;
    const int lo = t * per;
    const int hi = (lo + per < n) ? lo + per : n;
    int s = 0;
    for (int i = lo; i < hi; i++) s += edeg[i];
    partial[t] = s;
    __syncthreads();
    for (int off = 1; off < 256; off <<= 1) {
      int v = (t >= off) ? partial[t - off] : 0;
      __syncthreads();
      partial[t] += v;
      __syncthreads();
    }
    int run = (t > 0) ? partial[t - 1] : 0;
    for (int i = lo; i < hi; i++) {
      int d = edeg[i];
      rowstart[i] = run; run += d;
      dinv[i] = rsqrtf(1.0f + (float)d);
      edeg[i] = 0;
    }
    if (t == 255) rowstart[n] = run;
  } else if (blockIdx.x <= 4) {
    gemm_tile<true>(Wct, w2b, W2WcT, 128, 512, 512, 0, blockIdx.x - 1);
  } else {
    const int j = threadIdx.x;
    if (j < 128) {
      float s = 0.f;
      if (j < 100) {
        s = bc[j];
        for (int k = 0; k < 512; k++) s = fmaf(b2[k], Wc[k * 100 + j], s);
      }
      bias2c[j] = s;
    }
  }
}

// ================= kernel 3: gemm1 (fp32 A) + CSR fill (packed uint2) =================
__global__ __launch_bounds__(256)
void fill_gemm1(const float* __restrict__ x, const unsigned short* __restrict__ W1t,
                unsigned short* __restrict__ B2,
                const int* __restrict__ src, const int* __restrict__ dst,
                const float* __restrict__ dinv, const int* __restrict__ rowstart,
                int* __restrict__ cursor, uint2* __restrict__ csr, int E)
{
  if (blockIdx.x < 316) {
    gemm_tile_f32A(x, W1t, B2, NN, blockIdx.x >> 2, blockIdx.x & 3);
  } else {
    int e = (blockIdx.x - 316) * 256 + threadIdx.x;
    const int stride = 157 * 256;
    for (; e < E; e += stride) {
      int s = src[e], d = dst[e];
      int pos = rowstart[d] + atomicAdd(&cursor[d], 1);
      float nm = dinv[s] * dinv[d];
      csr[pos] = make_uint2((unsigned int)s, __float_as_uint(nm));
    }
  }
}

// ================= kernel 4: gather1 (full-row wave-per-node, 16B/lane) =================
__device__ __forceinline__ void acc8(float* a, uint4 v, float nm) {
  a[0] = fmaf(b2f((unsigned short)(v.x & 0xffffu)), nm, a[0]);
  a[1] = fmaf(b2f((unsigned short)(v.x >> 16)),     nm, a[1]);
  a[2] = fmaf(b2f((unsigned short)(v.y & 0xffffu)), nm, a[2]);
  a[3] = fmaf(b2f((unsigned short)(v.y >> 16)),     nm, a[3]);
  a[4] = fmaf(b2f((unsigned short)(v.z & 0xffffu)), nm, a[4]);
  a[5] = fmaf(b2f((unsigned short)(v.z >> 16)),     nm, a[5]);
  a[6] = fmaf(b2f((unsigned short)(v.w & 0xffffu)), nm, a[6]);
  a[7] = fmaf(b2f((unsigned short)(v.w >> 16)),     nm, a[7]);
}

__global__ __launch_bounds__(256)
void gather1(const unsigned short* __restrict__ h, const float* __restrict__ dinv,
             const int* __restrict__ rowstart, const uint2* __restrict__ csr,
             const float* __restrict__ bias, unsigned short* __restrict__ outb, int n)
{
  int node = blockIdx.x * 4 + (threadIdx.x >> 6);
  if (node >= n) return;
  const int lane = threadIdx.x & 63;
  const int c8 = lane * 8;

  float di = dinv[node];
  float slf = di * di;
  uint4 hv = *(const uint4*)&h[(size_t)node * 512 + c8];
  const float4* bp = (const float4*)&bias[c8];
  float4 b0 = bp[0], b1 = bp[1];
  float a[8] = {b0.x, b0.y, b0.z, b0.w, b1.x, b1.y, b1.z, b1.w};
  acc8(a, hv, slf);

  const int jb = rowstart[node], je = rowstart[node + 1];
  int j = jb;
  for (; j + 8 <= je; j += 8) {
    uint2 ee[8]; uint4 vv[8];
    #pragma unroll
    for (int q = 0; q < 8; q++) ee[q] = csr[j + q];
    #pragma unroll
    for (int q = 0; q < 8; q++) vv[q] = *(const uint4*)&h[(size_t)ee[q].x * 512 + c8];
    #pragma unroll
    for (int q = 0; q < 8; q++) acc8(a, vv[q], __uint_as_float(ee[q].y));
  }
  for (; j < je; ++j) {
    uint2 ee = csr[j];
    uint4 v = *(const uint4*)&h[(size_t)ee.x * 512 + c8];
    acc8(a, v, __uint_as_float(ee.y));
  }
  #pragma unroll
  for (int q = 0; q < 8; q++) a[q] = fmaxf(a[q], 0.f);
  uint4 o;
  o.x = (unsigned int)f2b(a[0]) | ((unsigned int)f2b(a[1]) << 16);
  o.y = (unsigned int)f2b(a[2]) | ((unsigned int)f2b(a[3]) << 16);
  o.z = (unsigned int)f2b(a[4]) | ((unsigned int)f2b(a[5]) << 16);
  o.w = (unsigned int)f2b(a[6]) | ((unsigned int)f2b(a[7]) << 16);
  *(uint4*)&outb[(size_t)node * 512 + c8] = o;
}

// ================= kernel 5: gemm2c: Z = B1 @ W2WcT^T (bf16 out, 128 cols) =================
__global__ __launch_bounds__(256)
void gemm2c(const unsigned short* __restrict__ B1, const unsigned short* __restrict__ W2WcT,
            unsigned short* __restrict__ Z)
{
  gemm_tile<true>(B1, W2WcT, Z, NN, 128, 128, blockIdx.x, 0);
}

// ================= kernel 6: gather2c (bf16 Z, full-row, 2 cols/lane) =================
__global__ __launch_bounds__(256)
void gather2c(const unsigned short* __restrict__ Z, const float* __restrict__ dinv,
              const int* __restrict__ rowstart, const uint2* __restrict__ csr,
              const float* __restrict__ bias2c, float* __restrict__ out, int n)
{
  int node = blockIdx.x * 4 + (threadIdx.x >> 6);
  if (node >= n) return;
  const int lane = threadIdx.x & 63;
  const int c2 = lane * 2;
  const float2 bb = *(const float2*)&bias2c[c2];

  float di = dinv[node];
  float slf = di * di;
  unsigned int hv = *(const unsigned int*)&Z[(size_t)node * 128 + c2];
  float a0 = fmaf(b2f((unsigned short)(hv & 0xffffu)), slf, bb.x);
  float a1 = fmaf(b2f((unsigned short)(hv >> 16)),     slf, bb.y);

  const int jb = rowstart[node], je = rowstart[node + 1];
  int j = jb;
  for (; j + 8 <= je; j += 8) {
    uint2 ee[8]; unsigned int vv[8];
    #pragma unroll
    for (int q = 0; q < 8; q++) ee[q] = csr[j + q];
    #pragma unroll
    for (int q = 0; q < 8; q++) vv[q] = *(const unsigned int*)&Z[(size_t)ee[q].x * 128 + c2];
    #pragma unroll
    for (int q = 0; q < 8; q++) {
      float nm = __uint_as_float(ee[q].y);
      a0 = fmaf(b2f((unsigned short)(vv[q] & 0xffffu)), nm, a0);
      a1 = fmaf(b2f((unsigned short)(vv[q] >> 16)),     nm, a1);
    }
  }
  for (; j < je; ++j) {
    uint2 ee = csr[j];
    unsigned int v = *(const unsigned int*)&Z[(size_t)ee.x * 128 + c2];
    float nm = __uint_as_float(ee.y);
    a0 = fmaf(b2f((unsigned short)(v & 0xffffu)), nm, a0);
    a1 = fmaf(b2f((unsigned short)(v >> 16)),     nm, a1);
  }
  if (c2 < 100)
    *(float2*)&out[(size_t)node * 100 + c2] = make_float2(a0, a1);
}

extern "C" void kernel_launch(void* const* d_in, const int* in_sizes, int n_in,
                              void* d_out, int out_size, void* d_ws, size_t ws_size,
                              hipStream_t stream) {
  const float* x  = (const float*)d_in[0];
  const int*   ei = (const int*)d_in[1];
  const float* W1 = (const float*)d_in[2];
  const float* b1 = (const float*)d_in[3];
  const float* W2 = (const float*)d_in[4];
  const float* b2 = (const float*)d_in[5];
  const float* Wc = (const float*)d_in[6];
  const float* bc = (const float*)d_in[7];
  float* out = (float*)d_out;

  const int n = NN;
  const int E = in_sizes[1] / 2;
  const int* src = ei;
  const int* dst = ei + E;

  // workspace (~27 MB)
  char* w = (char*)d_ws;
  int* edeg = (int*)w;                      w += ((n * 4 + 255) / 256) * 256;   // also fill cursor
  int* rowstart = (int*)w;                  w += (((n + 1) * 4 + 255) / 256) * 256;
  uint2* csr = (uint2*)w;                   w += ((E * 8 + 255) / 256) * 256;
  float* dinv = (float*)w;                  w += ((n * 4 + 255) / 256) * 256;
  float* bias2c = (float*)w;                w += 512;
  unsigned short* W1t = (unsigned short*)w; w += 512 * 512 * 2;
  unsigned short* Wct = (unsigned short*)w; w += 128 * 512 * 2;
  unsigned short* w2b = (unsigned short*)w; w += 512 * 512 * 2;
  unsigned short* W2WcT = (unsigned short*)w; w += 128 * 512 * 2;
  unsigned short* B1  = (unsigned short*)w; w += (size_t)n * 512 * 2;
  unsigned short* B2  = (unsigned short*)w; w += (size_t)n * 512 * 2;
  unsigned short* Z   = (unsigned short*)w; w += (size_t)n * 128 * 2;

  const int nb_g = (n + 3) / 4;

  hipMemsetAsync(edeg, 0, n * sizeof(int), stream);
  prep<<<512, 256, 0, stream>>>(W1, Wc, W2, dst, edeg, W1t, Wct, w2b, E);
  scan_plus<<<6, 256, 0, stream>>>(edeg, rowstart, dinv, Wct, w2b, W2WcT, b2, Wc, bc, bias2c, n);
  fill_gemm1<<<316 + 157, 256, 0, stream>>>(x, W1t, B2, src, dst, dinv, rowstart,
                                            edeg, csr, E);
  gather1<<<nb_g, 256, 0, stream>>>(B2, dinv, rowstart, csr, b1, B1, n);
  gemm2c<<<79, 256, 0, stream>>>(B1, W2WcT, Z);
  gather2c<<<nb_g, 256, 0, stream>>>(Z, dinv, rowstart, csr, bias2c, out, n);
}